// Round 11
// baseline (76.485 us; speedup 1.0000x reference)
//
#include <hip/hip_runtime.h>
#include <math.h>
#include <stdint.h>

#define K_NN   16
#define BATCH  2
#define NA_    16384
#define NB_    8192
#define CH     128
// coords are [z,y,x]: z in [0,64), y in [0,256), x in [0,256); cell edge 16
#define CZ     4
#define CY     16
#define CX     16
#define NCELL  (CZ*CY*CX)   // 1024
#define CSH    4
#define PADKEY 0xFFF00000u  // > any real key ((134019<<14)|16383 = 0x82E0BFFF)

__device__ __forceinline__ int cell_of(float p0, float p1, float p2) {
    const int cz = ((int)p0) >> CSH;   // z/16 in [0,4)
    const int cy = ((int)p1) >> CSH;   // y/16 in [0,16)
    const int cx = ((int)p2) >> CSH;   // x/16 in [0,16)
    return (cz * CY + cy) * CX + cx;
}

// ---------------- build: count (128 blocks) ----------------

__global__ void count_kernel(const float* __restrict__ tpos, int* __restrict__ counts) {
    int i = blockIdx.x * 256 + threadIdx.x;
    if (i >= BATCH * NA_) return;
    int b = i >> 14;
    const float* tp = tpos + (size_t)i * 3;
    atomicAdd(&counts[b * NCELL + cell_of(tp[0], tp[1], tp[2])], 1);
}

// ---------------- build: fused scan + scatter (1 block/batch, 1024 thr) ----------------

__global__ __launch_bounds__(1024) void scan_scatter(const float* __restrict__ tpos,
                                                     const int* __restrict__ counts,
                                                     int2* __restrict__ meta,
                                                     float4* __restrict__ sorted) {
    __shared__ int cur[NCELL];
    __shared__ int wp[16];
    const int b = blockIdx.x, t = threadIdx.x, lane = t & 63, w = t >> 6;

    const int c = counts[b * NCELL + t];
    int x = c;
#pragma unroll
    for (int off = 1; off < 64; off <<= 1) {
        int u = __shfl_up(x, off);
        if (lane >= off) x += u;
    }
    if (lane == 63) wp[w] = x;
    __syncthreads();
    if (t < 16) {
        int v = wp[t];
#pragma unroll
        for (int off = 1; off < 16; off <<= 1) {
            int u = __shfl_up(v, off);
            if (t >= off) v += u;
        }
        wp[t] = v;
    }
    __syncthreads();
    const int excl = x - c + (w ? wp[w - 1] : 0);
    meta[b * NCELL + t] = make_int2(excl, c);
    cur[t] = excl;
    __syncthreads();

    const float* tb = tpos + (size_t)b * NA_ * 3;
#pragma unroll
    for (int i = 0; i < 16; ++i) {
        const int pi = t + i * 1024;
        const float* p = tb + (size_t)pi * 3;
        const float p0 = p[0], p1 = p[1], p2 = p[2];
        const int cell = cell_of(p0, p1, p2);
        const int pos = atomicAdd(&cur[cell], 1);
        sorted[(size_t)b * NA_ + pos] = make_float4(p0, p1, p2, __int_as_float(pi));
    }
}

// ---------------- fallback merge: extract 16 smallest keys across the wave ----------------

template<int NS>
__device__ __forceinline__ void merge_extract(uint32_t (&k)[NS], uint32_t (&sel)[K_NN]) {
    uint32_t m = k[0];
#pragma unroll
    for (int j = 1; j < NS; ++j) m = min(m, k[j]);
#pragma unroll
    for (int r = 0; r < K_NN; ++r) {
        uint32_t v = m;
#pragma unroll
        for (int off = 32; off > 0; off >>= 1)
            v = min(v, (uint32_t)__shfl_xor((int)v, off));
        sel[r] = (uint32_t)__builtin_amdgcn_readfirstlane((int)v);
        if (m == v) {
#pragma unroll
            for (int j = 0; j < NS; ++j) k[j] = (k[j] == v) ? 0xFFFFFFFFu : k[j];
            m = k[0];
#pragma unroll
            for (int j = 1; j < NS; ++j) m = min(m, k[j]);
        }
    }
}

// ---------------- main KNN + aggregation ----------------

__global__ __launch_bounds__(256) void knn_cells_kernel(
    const float* __restrict__ tfeat,   // [B, NA, C]
    const float* __restrict__ spos,    // [B, NB, 3]
    const int2*  __restrict__ meta,    // [B, NCELL] (start, count)
    const float4* __restrict__ sorted, // [B, NA] (z,y,x,idx-bits)
    float* __restrict__ out)           // [B, NB, C]
{
    __shared__ uint32_t sKeys[4][132];  // compacted candidates, wave-private
    __shared__ uint32_t sSel[4][16];    // rank-ordered winners, wave-private

    const int tid  = threadIdx.x;
    const int lane = tid & 63;
    const int wave = tid >> 6;

    const int bpb = NB_ / 4;
    const int b = blockIdx.x / bpb;
    const int n = (blockIdx.x % bpb) * 4 + wave;

    const float* sp = spos + ((size_t)b * NB_ + n) * 3;
    const float s0 = sp[0], s1 = sp[1], s2 = sp[2];     // z, y, x
    const int scz = __builtin_amdgcn_readfirstlane(((int)s0) >> CSH);
    const int scy = __builtin_amdgcn_readfirstlane(((int)s1) >> CSH);
    const int scx = __builtin_amdgcn_readfirstlane(((int)s2) >> CSH);

    int rcov = max(max(scx, CX - 1 - scx), max(scy, CY - 1 - scy));
    rcov = max(rcov, max(scz, CZ - 1 - scz));

    const int2*   mb = meta   + (size_t)b * NCELL;
    const float4* sb = sorted + (size_t)b * NA_;

    // ---- 9 contiguous row-ranges of the 3x3x3 box (wave-uniform scalars) ----
    int rstart[9], rlen[9];
    const int cxlo = max(scx - 1, 0), cxhi = min(scx + 1, CX - 1);
    int nov = 0; bool fast = true;
#pragma unroll
    for (int kk = 0; kk < 9; ++kk) {
        const int cz = scz + kk / 3 - 1, cy = scy + kk % 3 - 1;
        int st = 0, ln = 0;
        if ((unsigned)cz < CZ && (unsigned)cy < CY) {
            const int rowb = (cz * CY + cy) * CX;
            const int2 mlo = mb[rowb + cxlo];
            const int2 mhi = mb[rowb + cxhi];
            st = mlo.x; ln = mhi.x + mhi.y - mlo.x;
        }
        rstart[kk] = st; rlen[kk] = ln;
        if (ln > 64) ++nov;
        if (ln > 128) fast = false;
    }
    if (nov > 3) fast = false;

    uint32_t sel[K_NN];
    bool done = false;

    if (fast) {
        // ---------- slotted scan: no selection logic ----------
        uint32_t key[12];
#pragma unroll
        for (int j = 0; j < 12; ++j) key[j] = PADKEY + j;
        int oc = 9;
#pragma unroll
        for (int kk = 0; kk < 9; ++kk) {
            if (rlen[kk] > 0) {
                const bool act = lane < rlen[kk];
                const int a = rstart[kk] + (act ? lane : 0);
                const float4 p = sb[a];
                const float d0 = s0 - p.x, d1 = s1 - p.y, d2c = s2 - p.z;
                const float d2 = d0 * d0 + d1 * d1 + d2c * d2c;
                const uint32_t kv = ((uint32_t)d2 << 14) | (uint32_t)__float_as_int(p.w);
                key[kk] = act ? kv : key[kk];
            }
            if (rlen[kk] > 64) {
                const int j2 = 64 + lane;
                const bool act = j2 < rlen[kk];
                const int a = rstart[kk] + (act ? j2 : 0);
                const float4 p = sb[a];
                const float d0 = s0 - p.x, d1 = s1 - p.y, d2c = s2 - p.z;
                const float d2 = d0 * d0 + d1 * d1 + d2c * d2c;
                const uint32_t kv = ((uint32_t)d2 << 14) | (uint32_t)__float_as_int(p.w);
                if (oc == 9)       key[9]  = act ? kv : key[9];
                else if (oc == 10) key[10] = act ? kv : key[10];
                else               key[11] = act ? kv : key[11];
                ++oc;
            }
        }

        // ---------- two-tier census (packed) ----------
        const uint32_t KT1 = 169u << 14;   // d^2 < 169
        const uint32_t KT2 = 288u << 14;   // d^2 < 288 (ring-1 stop: outside box >= 289)
        uint32_t pc = 0;
#pragma unroll
        for (int j = 0; j < 12; ++j) {
            pc += (key[j] < KT1) ? 1u : 0u;
            pc += (key[j] < KT2) ? 0x10000u : 0u;
        }
#pragma unroll
        for (int off = 32; off > 0; off >>= 1)
            pc += (uint32_t)__shfl_xor((int)pc, off);
        const uint32_t c1 = (uint32_t)__builtin_amdgcn_readfirstlane((int)(pc & 0xFFFFu));
        const uint32_t c2 = (uint32_t)__builtin_amdgcn_readfirstlane((int)(pc >> 16));
        uint32_t keyT = 0;
        if (c1 >= K_NN) keyT = KT1;
        else if (c2 >= K_NN) keyT = KT2;

        if (keyT) {
            // ---------- ballot compaction into wave-private LDS ----------
            int nsel = 0;
#pragma unroll
            for (int j = 0; j < 12; ++j) {
                const bool pred = key[j] < keyT;
                const unsigned long long m = __ballot(pred);
                const int offp = __builtin_amdgcn_mbcnt_hi(
                    (uint32_t)(m >> 32), __builtin_amdgcn_mbcnt_lo((uint32_t)m, 0));
                const int dst = nsel + offp;
                if (pred && dst < 132) sKeys[wave][dst] = key[j];
                nsel += (int)__builtin_popcountll(m);
            }

            if (nsel >= K_NN && nsel <= 128) {
                const int padn = (4 - (nsel & 3)) & 3;
                if (lane < padn) sKeys[wave][nsel + lane] = 0xFFFFFFFFu;
                __threadfence_block();

                const uint32_t myk0 = (lane      < nsel) ? sKeys[wave][lane]      : 0xFFFFFFFFu;
                const uint32_t myk1 = (64 + lane < nsel) ? sKeys[wave][64 + lane] : 0xFFFFFFFFu;

                uint32_t r0 = 0, r1 = 0;
                const int nmax4 = (nsel + 3) & ~3;
                for (int j = 0; j < nmax4; j += 4) {
                    const uint4 k4 = *(const uint4*)&sKeys[wave][j];
                    r0 += (k4.x < myk0) + (k4.y < myk0) + (k4.z < myk0) + (k4.w < myk0);
                    r1 += (k4.x < myk1) + (k4.y < myk1) + (k4.z < myk1) + (k4.w < myk1);
                }
                if (r0 < K_NN) sSel[wave][r0] = myk0;
                if (r1 < K_NN) sSel[wave][r1] = myk1;
                __threadfence_block();

                const uint4 sA = *(const uint4*)&sSel[wave][0];
                const uint4 sB = *(const uint4*)&sSel[wave][4];
                const uint4 sC = *(const uint4*)&sSel[wave][8];
                const uint4 sD = *(const uint4*)&sSel[wave][12];
                sel[0]  = (uint32_t)__builtin_amdgcn_readfirstlane((int)sA.x);
                sel[1]  = (uint32_t)__builtin_amdgcn_readfirstlane((int)sA.y);
                sel[2]  = (uint32_t)__builtin_amdgcn_readfirstlane((int)sA.z);
                sel[3]  = (uint32_t)__builtin_amdgcn_readfirstlane((int)sA.w);
                sel[4]  = (uint32_t)__builtin_amdgcn_readfirstlane((int)sB.x);
                sel[5]  = (uint32_t)__builtin_amdgcn_readfirstlane((int)sB.y);
                sel[6]  = (uint32_t)__builtin_amdgcn_readfirstlane((int)sB.z);
                sel[7]  = (uint32_t)__builtin_amdgcn_readfirstlane((int)sB.w);
                sel[8]  = (uint32_t)__builtin_amdgcn_readfirstlane((int)sC.x);
                sel[9]  = (uint32_t)__builtin_amdgcn_readfirstlane((int)sC.y);
                sel[10] = (uint32_t)__builtin_amdgcn_readfirstlane((int)sC.z);
                sel[11] = (uint32_t)__builtin_amdgcn_readfirstlane((int)sC.w);
                sel[12] = (uint32_t)__builtin_amdgcn_readfirstlane((int)sD.x);
                sel[13] = (uint32_t)__builtin_amdgcn_readfirstlane((int)sD.y);
                sel[14] = (uint32_t)__builtin_amdgcn_readfirstlane((int)sD.z);
                sel[15] = (uint32_t)__builtin_amdgcn_readfirstlane((int)sD.w);
                done = true;
            }
        }
    }

    if (!done) {
        // ---------- exact ring loop with insert path ----------
        for (int r = 1;; ++r) {
            uint32_t kl[K_NN];
#pragma unroll
            for (int j = 0; j < K_NN; ++j) kl[j] = PADKEY + 16 + j;
            if (r > 1) {
                uint32_t seed = 0xFFFFFFFFu;
#pragma unroll
                for (int j = 0; j < K_NN; ++j) if (lane == j) seed = sel[j];
                kl[0] = seed;
            }
            uint32_t curmax = kl[0];
#pragma unroll
            for (int j = 1; j < K_NN; ++j) curmax = max(curmax, kl[j]);

            for (int dz = -r; dz <= r; ++dz) {
                const int cz = scz + dz; if ((unsigned)cz >= CZ) continue;
                for (int dy = -r; dy <= r; ++dy) {
                    const int cy = scy + dy; if ((unsigned)cy >= CY) continue;
                    const int rowb = (cz * CY + cy) * CX;
                    const bool fullrow = (r == 1) || (max(abs(dz), abs(dy)) == r);
                    int xl[2], xh[2];
                    if (fullrow) {
                        xl[0] = max(scx - r, 0); xh[0] = min(scx + r, CX - 1);
                        xl[1] = 1; xh[1] = 0;
                    } else {
                        xl[0] = scx - r; xh[0] = scx - r;
                        xl[1] = scx + r; xh[1] = scx + r;
                        if (xl[0] < 0)      { xl[0] = 1; xh[0] = 0; }
                        if (xh[1] > CX - 1) { xl[1] = 1; xh[1] = 0; }
                    }
#pragma unroll
                    for (int q = 0; q < 2; ++q) {
                        if (xl[q] > xh[q]) continue;
                        const int2 mlo = mb[rowb + xl[q]];
                        const int2 mhi = mb[rowb + xh[q]];
                        const int st = mlo.x, ln = mhi.x + mhi.y - st;
                        for (int o = 0; o < ln; o += 64) {
                            const int j2 = o + lane;
                            const bool act = j2 < ln;
                            const int a = st + (act ? j2 : 0);
                            const float4 p = sb[a];
                            const float d0 = s0 - p.x, d1 = s1 - p.y, d2c = s2 - p.z;
                            const float d2 = d0 * d0 + d1 * d1 + d2c * d2c;
                            uint32_t kv = ((uint32_t)d2 << 14) | (uint32_t)__float_as_int(p.w);
                            kv = act ? kv : 0xFFFFFFFFu;
                            if (kv < curmax) {
#pragma unroll
                                for (int j = 0; j < K_NN; ++j)
                                    kl[j] = (kl[j] == curmax) ? kv : kl[j];
                                curmax = kl[0];
#pragma unroll
                                for (int j = 1; j < K_NN; ++j) curmax = max(curmax, kl[j]);
                            }
                        }
                    }
                }
            }
            merge_extract<K_NN>(kl, sel);
            const uint32_t d16 = sel[K_NN - 1] >> 14;
            if (d16 <= (uint32_t)(256 * r * r) || r >= rcov) break;
        }
    }

    // ---- weights + normalized feature aggregation (float2 per lane) ----
    float w[K_NN];
    float wsum = 0.f;
#pragma unroll
    for (int j = 0; j < K_NN; ++j) {
        w[j] = __expf(-0.5f * (float)(sel[j] >> 14));
        wsum += w[j];
    }
    const float inv = 1.0f / wsum;

    const float* fb = tfeat + (size_t)b * NA_ * CH;
    float2 acc = make_float2(0.f, 0.f);
#pragma unroll
    for (int j = 0; j < K_NN; ++j) {
        const int idx = (int)(sel[j] & 16383u);
        const float ww = w[j] * inv;
        const float2 v = ((const float2*)(fb + (size_t)idx * CH))[lane];
        acc.x += ww * v.x; acc.y += ww * v.y;
    }

    float2* o = (float2*)(out + ((size_t)b * NB_ + n) * CH);
    o[lane] = acc;
}

// ---------------- launch ----------------

extern "C" void kernel_launch(void* const* d_in, const int* in_sizes, int n_in,
                              void* d_out, int out_size, void* d_ws, size_t ws_size,
                              hipStream_t stream) {
    const float* tfeat = (const float*)d_in[0];   // [B,NA,C]
    const float* tpos  = (const float*)d_in[1];   // [B,NA,3]
    const float* spos  = (const float*)d_in[2];   // [B,NB,3]
    float* out = (float*)d_out;                   // [B,NB,C]

    char* ws = (char*)d_ws;
    int*    counts = (int*)(ws);                  // 8 KiB
    int2*   meta   = (int2*)(ws + 8192);          // 16 KiB
    float4* sorted = (float4*)(ws + 32768);       // 512 KiB

    hipMemsetAsync(counts, 0, BATCH * NCELL * sizeof(int), stream);
    count_kernel<<<(BATCH * NA_) / 256, 256, 0, stream>>>(tpos, counts);
    scan_scatter<<<BATCH, 1024, 0, stream>>>(tpos, counts, meta, sorted);
    knn_cells_kernel<<<BATCH * (NB_ / 4), 256, 0, stream>>>(tfeat, spos, meta, sorted, out);
}

// Round 12
// 74.310 us; speedup vs baseline: 1.0293x; 1.0293x over previous
//
#include <hip/hip_runtime.h>
#include <math.h>
#include <stdint.h>

#define K_NN   16
#define BATCH  2
#define NA_    16384
#define NB_    8192
#define CH     128
// coords are [z,y,x]: z in [0,64), y in [0,256), x in [0,256); cell edge 16
#define CZ     4
#define CY     16
#define CX     16
#define NCELL  (CZ*CY*CX)   // 1024
#define CSH    4
#define CAP    32           // bucket capacity; P(Poisson(16)>32) ~ 1e-5 per cell
#define OVFCAP 2048
#define PADKEY 0xFFF00000u  // > any real key ((134019<<14)|16383 = 0x82E0BFFF)

// ws layout:
//   counts : [B][NCELL] int     @ 0       (8 KiB)
//   ovfcnt : [B] int            @ 8192
//   ovfbuf : [B][OVFCAP] float4 @ 16384   (64 KiB)
//   buckets: [B][NCELL][CAP] f4 @ 81920   (1 MiB)
#define OFF_OVFCNT 8192
#define OFF_OVFBUF 16384
#define OFF_BUCKET 81920

__device__ __forceinline__ int cell_of(float p0, float p1, float p2) {
    const int cz = ((int)p0) >> CSH;
    const int cy = ((int)p1) >> CSH;
    const int cx = ((int)p2) >> CSH;
    return (cz * CY + cy) * CX + cx;
}

// ---------------- init: sentinel-fill buckets + zero counts/ovfcnt ----------------

__global__ __launch_bounds__(256) void init_kernel(int* __restrict__ counts,
                                                   int* __restrict__ ovfcnt,
                                                   float4* __restrict__ buckets) {
    const int i = blockIdx.x * 256 + threadIdx.x;      // 0 .. B*NCELL*CAP-1 (65536)
    buckets[i] = make_float4(-512.f, -512.f, -512.f, 0.f);
    if (i < BATCH * NCELL) counts[i] = 0;
    if (i < BATCH) ovfcnt[i] = 0;
}

// ---------------- one-pass bucketed build (128 blocks) ----------------

__global__ __launch_bounds__(256) void bucket_build(const float* __restrict__ tpos,
                                                    int* __restrict__ counts,
                                                    int* __restrict__ ovfcnt,
                                                    float4* __restrict__ ovfbuf,
                                                    float4* __restrict__ buckets) {
    const int i = blockIdx.x * 256 + threadIdx.x;      // over B*NA (= 32768)
    const int b = i >> 14;
    const float* p = tpos + (size_t)i * 3;
    const float p0 = p[0], p1 = p[1], p2 = p[2];
    const int cell = b * NCELL + cell_of(p0, p1, p2);
    const int pos = atomicAdd(&counts[cell], 1);
    const float4 v = make_float4(p0, p1, p2, __int_as_float(i & (NA_ - 1)));
    if (pos < CAP) {
        buckets[(size_t)cell * CAP + pos] = v;
    } else {
        const int o = atomicAdd(&ovfcnt[b], 1);
        if (o < OVFCAP) ovfbuf[b * OVFCAP + o] = v;
    }
}

// ---------------- exact ring fallback (rare; results -> wave-private LDS) ----------------

__device__ __noinline__ void ring_fallback(int lane, float s0, float s1, float s2,
                                           int scz, int scy, int scx, int rcov,
                                           const int* __restrict__ cb,
                                           const float4* __restrict__ bk,
                                           int ovfn, const float4* __restrict__ ovfp,
                                           uint32_t* selLds) {
    uint32_t sel[K_NN];
#pragma unroll
    for (int j = 0; j < K_NN; ++j) sel[j] = 0xFFFFFFFFu;

    for (int r = 1;; ++r) {
        uint32_t kl[K_NN];
#pragma unroll
        for (int j = 0; j < K_NN; ++j) kl[j] = PADKEY + 16 + j;
        if (r > 1) {
            uint32_t seed = 0xFFFFFFFFu;
#pragma unroll
            for (int j = 0; j < K_NN; ++j) if (lane == j) seed = sel[j];
            kl[0] = seed;
        }
        uint32_t curmax = kl[0];
#pragma unroll
        for (int j = 1; j < K_NN; ++j) curmax = max(curmax, kl[j]);

        auto ins = [&](float4 p, bool act) {
            const float d0 = s0 - p.x, d1 = s1 - p.y, d2c = s2 - p.z;
            const float d2 = d0 * d0 + d1 * d1 + d2c * d2c;
            uint32_t kv = ((uint32_t)d2 << 14) | (uint32_t)__float_as_int(p.w);
            kv = act ? kv : 0xFFFFFFFFu;
            if (kv < curmax) {
#pragma unroll
                for (int j = 0; j < K_NN; ++j)
                    kl[j] = (kl[j] == curmax) ? kv : kl[j];
                curmax = kl[0];
#pragma unroll
                for (int j = 1; j < K_NN; ++j) curmax = max(curmax, kl[j]);
            }
        };

        // overflow points examined once at r==1
        if (r == 1 && ovfn > 0) {
            for (int o = 0; o < ovfn; o += 64) {
                const int j2 = o + lane;
                const bool act = j2 < ovfn;
                ins(ovfp[act ? j2 : 0], act);
            }
        }

        for (int dz = -r; dz <= r; ++dz) {
            const int cz = scz + dz; if ((unsigned)cz >= CZ) continue;
            for (int dy = -r; dy <= r; ++dy) {
                const int cy = scy + dy; if ((unsigned)cy >= CY) continue;
                const int rowb = (cz * CY + cy) * CX;
                const bool fullrow = (r == 1) || (max(abs(dz), abs(dy)) == r);
                int xl[2], xh[2];
                if (fullrow) {
                    xl[0] = max(scx - r, 0); xh[0] = min(scx + r, CX - 1);
                    xl[1] = 1; xh[1] = 0;
                } else {
                    xl[0] = scx - r; xh[0] = scx - r;
                    xl[1] = scx + r; xh[1] = scx + r;
                    if (xl[0] < 0)      { xl[0] = 1; xh[0] = 0; }
                    if (xh[1] > CX - 1) { xl[1] = 1; xh[1] = 0; }
                }
#pragma unroll
                for (int q = 0; q < 2; ++q) {
                    for (int cx = xl[q]; cx <= xh[q]; ++cx) {
                        const int cell = rowb + cx;
                        const int ln = min(cb[cell], CAP);
                        if (ln <= 0) continue;
                        const bool act = lane < ln;
                        ins(bk[(size_t)cell * CAP + (act ? lane : 0)], act);
                    }
                }
            }
        }

        uint32_t m = kl[0];
#pragma unroll
        for (int j = 1; j < K_NN; ++j) m = min(m, kl[j]);
#pragma unroll
        for (int rr = 0; rr < K_NN; ++rr) {
            uint32_t v = m;
#pragma unroll
            for (int off = 32; off > 0; off >>= 1)
                v = min(v, (uint32_t)__shfl_xor((int)v, off));
            sel[rr] = (uint32_t)__builtin_amdgcn_readfirstlane((int)v);
            if (m == v) {
#pragma unroll
                for (int j = 0; j < K_NN; ++j) kl[j] = (kl[j] == v) ? 0xFFFFFFFFu : kl[j];
                m = kl[0];
#pragma unroll
                for (int j = 1; j < K_NN; ++j) m = min(m, kl[j]);
            }
        }

        const uint32_t d16 = sel[K_NN - 1] >> 14;
        if (d16 <= (uint32_t)(256 * r * r) || r >= rcov) break;
    }

    if (lane == 0) {
#pragma unroll
        for (int j = 0; j < K_NN; ++j) selLds[j] = sel[j];
    }
}

// ---------------- main KNN + aggregation: sentinel buckets, meta-free fast path ----------------

__global__ __launch_bounds__(256) void knn_cells_kernel(
    const float* __restrict__ tfeat,   // [B, NA, C]
    const float* __restrict__ spos,    // [B, NB, 3]
    const int*   __restrict__ counts,  // [B, NCELL]
    const float4* __restrict__ buckets,// [B, NCELL, CAP]
    const int*   __restrict__ ovfcnt,  // [B]
    const float4* __restrict__ ovfbuf, // [B, OVFCAP]
    float* __restrict__ out)           // [B, NB, C]
{
    __shared__ uint32_t sKeys[4][132];
    __shared__ uint32_t sSel[4][16];

    const int tid  = threadIdx.x;
    const int lane = tid & 63;
    const int wave = tid >> 6;

    const int bpb = NB_ / 4;
    const int b = blockIdx.x / bpb;
    const int n = (blockIdx.x % bpb) * 4 + wave;

    const int*    cb = counts  + (size_t)b * NCELL;
    const float4* bk = buckets + (size_t)b * NCELL * CAP;
    const int ovfn = __builtin_amdgcn_readfirstlane(ovfcnt[b]);

    const float* sp = spos + ((size_t)b * NB_ + n) * 3;
    const float s0 = sp[0], s1 = sp[1], s2 = sp[2];   // z, y, x
    const int scz = __builtin_amdgcn_readfirstlane(((int)s0) >> CSH);
    const int scy = __builtin_amdgcn_readfirstlane(((int)s1) >> CSH);
    const int scx = __builtin_amdgcn_readfirstlane(((int)s2) >> CSH);
    int rcov = max(max(scx, CX - 1 - scx), max(scy, CY - 1 - scy));
    rcov = max(rcov, max(scz, CZ - 1 - scz));

    const int cxlo = max(scx - 1, 0), cxhi = min(scx + 1, CX - 1);
    const int m3 = cxhi - cxlo;                 // 1 (x-edge) or 2

    // ---- 9 row bases (wave-uniform); invalid rows skipped uniformly ----
    int  rbase[9];
    bool rvalid[9];
#pragma unroll
    for (int kk = 0; kk < 9; ++kk) {
        const int cz = scz + kk / 3 - 1, cy = scy + kk % 3 - 1;
        rvalid[kk] = ((unsigned)cz < CZ) && ((unsigned)cy < CY);
        rbase[kk] = (((cz * CY + cy) * CX) + cxlo) * CAP;
    }

    // ---- sentinel-filtered key scan: 9 full chunks + 5 paired half-chunks ----
    uint32_t key[14];
#pragma unroll
    for (int kk = 0; kk < 9; ++kk) {
        if (rvalid[kk]) {
            const float4 p = bk[rbase[kk] + lane];
            const float d0 = s0 - p.x, d1 = s1 - p.y, d2c = s2 - p.z;
            const float d2 = d0 * d0 + d1 * d1 + d2c * d2c;
            const uint32_t kv = ((uint32_t)d2 << 14) | (uint32_t)__float_as_int(p.w);
            key[kk] = (d2 <= 288.0f) ? kv : (PADKEY + kk);
        } else {
            key[kk] = PADKEY + kk;
        }
    }
#pragma unroll
    for (int h = 0; h < 5; ++h) {
        const int ra = 2 * h, rb = 2 * h + 1;
        if (m3 == 2) {
            const bool actA = rvalid[ra];
            const bool actB = (rb < 9) && rvalid[rb];
            const bool act = (lane < 32) ? actA : actB;
            const int addr = (lane < 32) ? (rbase[ra] + 64 + lane)
                                         : (rbase[rb < 9 ? rb : 0] + 32 + lane);
            const float4 p = bk[act ? addr : 0];
            const float d0 = s0 - p.x, d1 = s1 - p.y, d2c = s2 - p.z;
            const float d2 = d0 * d0 + d1 * d1 + d2c * d2c;
            const uint32_t kv = ((uint32_t)d2 << 14) | (uint32_t)__float_as_int(p.w);
            key[9 + h] = (act && d2 <= 288.0f) ? kv : (PADKEY + 9 + h);
        } else {
            key[9 + h] = PADKEY + 9 + h;
        }
    }

    // ---- two-tier census (packed) ----
    const uint32_t KT1 = 169u << 14;   // d^2 <= 168
    const uint32_t KT2 = 289u << 14;   // d^2 <= 288 (stop: outside box >= 289)
    uint32_t pc = 0;
#pragma unroll
    for (int j = 0; j < 14; ++j) {
        pc += (key[j] < KT1) ? 1u : 0u;
        pc += (key[j] < KT2) ? 0x10000u : 0u;
    }
#pragma unroll
    for (int off = 32; off > 0; off >>= 1)
        pc += (uint32_t)__shfl_xor((int)pc, off);
    const uint32_t c1 = (uint32_t)__builtin_amdgcn_readfirstlane((int)(pc & 0xFFFFu));
    const uint32_t c2 = (uint32_t)__builtin_amdgcn_readfirstlane((int)(pc >> 16));
    uint32_t keyT = 0;
    if (ovfn == 0) {
        if (c1 >= K_NN) keyT = KT1;
        else if (c2 >= K_NN) keyT = KT2;
    }

    uint32_t sel[K_NN];
    bool ok = false;
    if (keyT) {
        // ---- ballot compaction into wave-private LDS ----
        int nsel = 0;
#pragma unroll
        for (int j = 0; j < 14; ++j) {
            const bool pred = key[j] < keyT;
            const unsigned long long m = __ballot(pred);
            const int offp = __builtin_amdgcn_mbcnt_hi(
                (uint32_t)(m >> 32), __builtin_amdgcn_mbcnt_lo((uint32_t)m, 0));
            const int dst = nsel + offp;
            if (pred && dst < 132) sKeys[wave][dst] = key[j];
            nsel += (int)__builtin_popcountll(m);
        }

        if (nsel >= K_NN && nsel <= 128) {
            const int padn = (4 - (nsel & 3)) & 3;
            if (lane < padn) sKeys[wave][nsel + lane] = 0xFFFFFFFFu;
            __threadfence_block();

            const uint32_t myk0 = (lane      < nsel) ? sKeys[wave][lane]      : 0xFFFFFFFFu;
            const uint32_t myk1 = (64 + lane < nsel) ? sKeys[wave][64 + lane] : 0xFFFFFFFFu;
            uint32_t r0 = 0, r1 = 0;
            const int nmax4 = (nsel + 3) & ~3;
            for (int j = 0; j < nmax4; j += 4) {
                const uint4 k4 = *(const uint4*)&sKeys[wave][j];
                r0 += (k4.x < myk0) + (k4.y < myk0) + (k4.z < myk0) + (k4.w < myk0);
                r1 += (k4.x < myk1) + (k4.y < myk1) + (k4.z < myk1) + (k4.w < myk1);
            }
            if (r0 < K_NN) sSel[wave][r0] = myk0;
            if (r1 < K_NN) sSel[wave][r1] = myk1;
            ok = true;
        }
    }
    if (!ok)
        ring_fallback(lane, s0, s1, s2, scz, scy, scx, rcov, cb, bk,
                      ovfn, ovfbuf + b * OVFCAP, &sSel[wave][0]);
    __threadfence_block();

    // ---- broadcast winners -> wave-uniform registers ----
    const uint4 sA = *(const uint4*)&sSel[wave][0];
    const uint4 sB = *(const uint4*)&sSel[wave][4];
    const uint4 sC = *(const uint4*)&sSel[wave][8];
    const uint4 sD = *(const uint4*)&sSel[wave][12];
    sel[0]  = (uint32_t)__builtin_amdgcn_readfirstlane((int)sA.x);
    sel[1]  = (uint32_t)__builtin_amdgcn_readfirstlane((int)sA.y);
    sel[2]  = (uint32_t)__builtin_amdgcn_readfirstlane((int)sA.z);
    sel[3]  = (uint32_t)__builtin_amdgcn_readfirstlane((int)sA.w);
    sel[4]  = (uint32_t)__builtin_amdgcn_readfirstlane((int)sB.x);
    sel[5]  = (uint32_t)__builtin_amdgcn_readfirstlane((int)sB.y);
    sel[6]  = (uint32_t)__builtin_amdgcn_readfirstlane((int)sB.z);
    sel[7]  = (uint32_t)__builtin_amdgcn_readfirstlane((int)sB.w);
    sel[8]  = (uint32_t)__builtin_amdgcn_readfirstlane((int)sC.x);
    sel[9]  = (uint32_t)__builtin_amdgcn_readfirstlane((int)sC.y);
    sel[10] = (uint32_t)__builtin_amdgcn_readfirstlane((int)sC.z);
    sel[11] = (uint32_t)__builtin_amdgcn_readfirstlane((int)sC.w);
    sel[12] = (uint32_t)__builtin_amdgcn_readfirstlane((int)sD.x);
    sel[13] = (uint32_t)__builtin_amdgcn_readfirstlane((int)sD.y);
    sel[14] = (uint32_t)__builtin_amdgcn_readfirstlane((int)sD.z);
    sel[15] = (uint32_t)__builtin_amdgcn_readfirstlane((int)sD.w);

    // ---- weights + normalized feature aggregation (float2 per lane) ----
    float w[K_NN];
    float wsum = 0.f;
#pragma unroll
    for (int j = 0; j < K_NN; ++j) {
        w[j] = __expf(-0.5f * (float)(sel[j] >> 14));
        wsum += w[j];
    }
    const float inv = 1.0f / wsum;

    const float* fb = tfeat + (size_t)b * NA_ * CH;
    float2 acc = make_float2(0.f, 0.f);
#pragma unroll
    for (int j = 0; j < K_NN; ++j) {
        const int idx = (int)(sel[j] & 16383u);
        const float ww = w[j] * inv;
        const float2 v = ((const float2*)(fb + (size_t)idx * CH))[lane];
        acc.x += ww * v.x; acc.y += ww * v.y;
    }

    float2* o = (float2*)(out + ((size_t)b * NB_ + n) * CH);
    o[lane] = acc;
}

// ---------------- launch ----------------

extern "C" void kernel_launch(void* const* d_in, const int* in_sizes, int n_in,
                              void* d_out, int out_size, void* d_ws, size_t ws_size,
                              hipStream_t stream) {
    const float* tfeat = (const float*)d_in[0];   // [B,NA,C]
    const float* tpos  = (const float*)d_in[1];   // [B,NA,3]
    const float* spos  = (const float*)d_in[2];   // [B,NB,3]
    float* out = (float*)d_out;                   // [B,NB,C]

    char* ws = (char*)d_ws;
    int*    counts  = (int*)(ws);
    int*    ovfcnt  = (int*)(ws + OFF_OVFCNT);
    float4* ovfbuf  = (float4*)(ws + OFF_OVFBUF);
    float4* buckets = (float4*)(ws + OFF_BUCKET);

    init_kernel<<<(BATCH * NCELL * CAP) / 256, 256, 0, stream>>>(counts, ovfcnt, buckets);
    bucket_build<<<(BATCH * NA_) / 256, 256, 0, stream>>>(tpos, counts, ovfcnt,
                                                          ovfbuf, buckets);
    knn_cells_kernel<<<BATCH * (NB_ / 4), 256, 0, stream>>>(tfeat, spos, counts,
                                                            buckets, ovfcnt, ovfbuf, out);
}

// Round 13
// 60.960 us; speedup vs baseline: 1.2547x; 1.2190x over previous
//
#include <hip/hip_runtime.h>
#include <math.h>
#include <stdint.h>

#define K_NN   16
#define BATCH  2
#define NA_    16384
#define NB_    8192
#define CH     128
// coords are [z,y,x]: z in [0,64), y in [0,256), x in [0,256); cell edge 16
#define CZ     4
#define CY     16
#define CX     16
#define NCELL  (CZ*CY*CX)   // 1024
#define CSH    4
#define PADKEY 0xFFF00000u  // > any real key ((134019<<14)|16383 = 0x82E0BFFF)

// ws layout:
//   partial: [16][NCELL] int   @ 0      (64 KiB)
//   meta   : [B][NCELL] int2   @ 65536  (16 KiB)
//   cursor : [B][NCELL] int    @ 81920  (8 KiB)
//   sorted : [B][NA] float4    @ 98304  (512 KiB)
#define OFF_META   65536
#define OFF_CURSOR 81920
#define OFF_SORTED 98304

__device__ __forceinline__ int cell_of(float p0, float p1, float p2) {
    const int cz = ((int)p0) >> CSH;   // z/16 in [0,4)
    const int cy = ((int)p1) >> CSH;   // y/16 in [0,16)
    const int cx = ((int)p2) >> CSH;   // x/16 in [0,16)
    return (cz * CY + cy) * CX + cx;
}

// ---------------- build 1: LDS-privatized histograms (16 blocks, no memset needed) ----------------

__global__ __launch_bounds__(256) void count_hist(const float* __restrict__ tpos,
                                                  int* __restrict__ partial) {
    __shared__ int h[NCELL];
    const int blk = blockIdx.x;            // 16 blocks; 0-7 batch0, 8-15 batch1
    const int t = threadIdx.x;
#pragma unroll
    for (int j = 0; j < NCELL / 256; ++j) h[t + j * 256] = 0;
    __syncthreads();
    const int base = blk * 2048;
#pragma unroll
    for (int i = 0; i < 8; ++i) {
        const float* p = tpos + (size_t)(base + i * 256 + t) * 3;
        atomicAdd(&h[cell_of(p[0], p[1], p[2])], 1);
    }
    __syncthreads();
#pragma unroll
    for (int j = 0; j < NCELL / 256; ++j) {
        const int c = t + j * 256;
        partial[blk * NCELL + c] = h[c];
    }
}

// ---------------- build 2: sum partials + scan (2 blocks x 1024) ----------------

__global__ __launch_bounds__(1024) void scan_kernel(const int* __restrict__ partial,
                                                    int2* __restrict__ meta,
                                                    int* __restrict__ cursor) {
    __shared__ int wp[16];
    const int b = blockIdx.x, t = threadIdx.x, lane = t & 63, w = t >> 6;
    int c = 0;
#pragma unroll
    for (int k = 0; k < 8; ++k) c += partial[(b * 8 + k) * NCELL + t];
    int x = c;
#pragma unroll
    for (int off = 1; off < 64; off <<= 1) {
        int u = __shfl_up(x, off);
        if (lane >= off) x += u;
    }
    if (lane == 63) wp[w] = x;
    __syncthreads();
    if (t < 16) {
        int v = wp[t];
#pragma unroll
        for (int off = 1; off < 16; off <<= 1) {
            int u = __shfl_up(v, off);
            if (t >= off) v += u;
        }
        wp[t] = v;
    }
    __syncthreads();
    const int excl = x - c + (w ? wp[w - 1] : 0);
    meta[b * NCELL + t]   = make_int2(excl, c);
    cursor[b * NCELL + t] = excl;
}

// ---------------- build 3: wide scatter (128 blocks) ----------------

__global__ __launch_bounds__(256) void scatter_kernel(const float* __restrict__ tpos,
                                                      int* __restrict__ cursor,
                                                      float4* __restrict__ sorted) {
    const int i = blockIdx.x * 256 + threadIdx.x;      // over B*NA
    const int b = i >> 14;
    const float* tp = tpos + (size_t)i * 3;
    const float p0 = tp[0], p1 = tp[1], p2 = tp[2];
    const int cell = cell_of(p0, p1, p2);
    const int pos = atomicAdd(&cursor[b * NCELL + cell], 1);
    sorted[(size_t)b * NA_ + pos] = make_float4(p0, p1, p2, __int_as_float(i & (NA_ - 1)));
}

// ---------------- fallback merge: extract 16 smallest keys across the wave ----------------

template<int NS>
__device__ __forceinline__ void merge_extract(uint32_t (&k)[NS], uint32_t (&sel)[K_NN]) {
    uint32_t m = k[0];
#pragma unroll
    for (int j = 1; j < NS; ++j) m = min(m, k[j]);
#pragma unroll
    for (int r = 0; r < K_NN; ++r) {
        uint32_t v = m;
#pragma unroll
        for (int off = 32; off > 0; off >>= 1)
            v = min(v, (uint32_t)__shfl_xor((int)v, off));
        sel[r] = (uint32_t)__builtin_amdgcn_readfirstlane((int)v);
        if (m == v) {
#pragma unroll
            for (int j = 0; j < NS; ++j) k[j] = (k[j] == v) ? 0xFFFFFFFFu : k[j];
            m = k[0];
#pragma unroll
            for (int j = 1; j < NS; ++j) m = min(m, k[j]);
        }
    }
}

// ---------------- main KNN + aggregation (R11 structure, measured 45.6 us) ----------------

__global__ __launch_bounds__(256) void knn_cells_kernel(
    const float* __restrict__ tfeat,   // [B, NA, C]
    const float* __restrict__ spos,    // [B, NB, 3]
    const int2*  __restrict__ meta,    // [B, NCELL] (start, count)
    const float4* __restrict__ sorted, // [B, NA] (z,y,x,idx-bits)
    float* __restrict__ out)           // [B, NB, C]
{
    __shared__ uint32_t sKeys[4][132];
    __shared__ uint32_t sSel[4][16];

    const int tid  = threadIdx.x;
    const int lane = tid & 63;
    const int wave = tid >> 6;

    const int bpb = NB_ / 4;
    const int b = blockIdx.x / bpb;
    const int n = (blockIdx.x % bpb) * 4 + wave;

    const float* sp = spos + ((size_t)b * NB_ + n) * 3;
    const float s0 = sp[0], s1 = sp[1], s2 = sp[2];     // z, y, x
    const int scz = __builtin_amdgcn_readfirstlane(((int)s0) >> CSH);
    const int scy = __builtin_amdgcn_readfirstlane(((int)s1) >> CSH);
    const int scx = __builtin_amdgcn_readfirstlane(((int)s2) >> CSH);

    int rcov = max(max(scx, CX - 1 - scx), max(scy, CY - 1 - scy));
    rcov = max(rcov, max(scz, CZ - 1 - scz));

    const int2*   mb = meta   + (size_t)b * NCELL;
    const float4* sb = sorted + (size_t)b * NA_;

    // ---- 9 contiguous row-ranges of the 3x3x3 box (wave-uniform scalars) ----
    int rstart[9], rlen[9];
    const int cxlo = max(scx - 1, 0), cxhi = min(scx + 1, CX - 1);
    int nov = 0; bool fast = true;
#pragma unroll
    for (int kk = 0; kk < 9; ++kk) {
        const int cz = scz + kk / 3 - 1, cy = scy + kk % 3 - 1;
        int st = 0, ln = 0;
        if ((unsigned)cz < CZ && (unsigned)cy < CY) {
            const int rowb = (cz * CY + cy) * CX;
            const int2 mlo = mb[rowb + cxlo];
            const int2 mhi = mb[rowb + cxhi];
            st = mlo.x; ln = mhi.x + mhi.y - mlo.x;
        }
        rstart[kk] = st; rlen[kk] = ln;
        if (ln > 64) ++nov;
        if (ln > 128) fast = false;
    }
    if (nov > 3) fast = false;

    uint32_t sel[K_NN];
    bool done = false;

    if (fast) {
        // ---------- slotted scan: no selection logic ----------
        uint32_t key[12];
#pragma unroll
        for (int j = 0; j < 12; ++j) key[j] = PADKEY + j;
        int oc = 9;
#pragma unroll
        for (int kk = 0; kk < 9; ++kk) {
            if (rlen[kk] > 0) {
                const bool act = lane < rlen[kk];
                const int a = rstart[kk] + (act ? lane : 0);
                const float4 p = sb[a];
                const float d0 = s0 - p.x, d1 = s1 - p.y, d2c = s2 - p.z;
                const float d2 = d0 * d0 + d1 * d1 + d2c * d2c;
                const uint32_t kv = ((uint32_t)d2 << 14) | (uint32_t)__float_as_int(p.w);
                key[kk] = act ? kv : key[kk];
            }
            if (rlen[kk] > 64) {
                const int j2 = 64 + lane;
                const bool act = j2 < rlen[kk];
                const int a = rstart[kk] + (act ? j2 : 0);
                const float4 p = sb[a];
                const float d0 = s0 - p.x, d1 = s1 - p.y, d2c = s2 - p.z;
                const float d2 = d0 * d0 + d1 * d1 + d2c * d2c;
                const uint32_t kv = ((uint32_t)d2 << 14) | (uint32_t)__float_as_int(p.w);
                if (oc == 9)       key[9]  = act ? kv : key[9];
                else if (oc == 10) key[10] = act ? kv : key[10];
                else               key[11] = act ? kv : key[11];
                ++oc;
            }
        }

        // ---------- two-tier census (packed) ----------
        const uint32_t KT1 = 169u << 14;   // d^2 < 169
        const uint32_t KT2 = 288u << 14;   // d^2 < 288 (ring-1 stop: outside box >= 289)
        uint32_t pc = 0;
#pragma unroll
        for (int j = 0; j < 12; ++j) {
            pc += (key[j] < KT1) ? 1u : 0u;
            pc += (key[j] < KT2) ? 0x10000u : 0u;
        }
#pragma unroll
        for (int off = 32; off > 0; off >>= 1)
            pc += (uint32_t)__shfl_xor((int)pc, off);
        const uint32_t c1 = (uint32_t)__builtin_amdgcn_readfirstlane((int)(pc & 0xFFFFu));
        const uint32_t c2 = (uint32_t)__builtin_amdgcn_readfirstlane((int)(pc >> 16));
        uint32_t keyT = 0;
        if (c1 >= K_NN) keyT = KT1;
        else if (c2 >= K_NN) keyT = KT2;

        if (keyT) {
            // ---------- ballot compaction into wave-private LDS ----------
            int nsel = 0;
#pragma unroll
            for (int j = 0; j < 12; ++j) {
                const bool pred = key[j] < keyT;
                const unsigned long long m = __ballot(pred);
                const int offp = __builtin_amdgcn_mbcnt_hi(
                    (uint32_t)(m >> 32), __builtin_amdgcn_mbcnt_lo((uint32_t)m, 0));
                const int dst = nsel + offp;
                if (pred && dst < 132) sKeys[wave][dst] = key[j];
                nsel += (int)__builtin_popcountll(m);
            }

            if (nsel >= K_NN && nsel <= 128) {
                const int padn = (4 - (nsel & 3)) & 3;
                if (lane < padn) sKeys[wave][nsel + lane] = 0xFFFFFFFFu;
                __threadfence_block();

                const uint32_t myk0 = (lane      < nsel) ? sKeys[wave][lane]      : 0xFFFFFFFFu;
                const uint32_t myk1 = (64 + lane < nsel) ? sKeys[wave][64 + lane] : 0xFFFFFFFFu;

                uint32_t r0 = 0, r1 = 0;
                const int nmax4 = (nsel + 3) & ~3;
                for (int j = 0; j < nmax4; j += 4) {
                    const uint4 k4 = *(const uint4*)&sKeys[wave][j];
                    r0 += (k4.x < myk0) + (k4.y < myk0) + (k4.z < myk0) + (k4.w < myk0);
                    r1 += (k4.x < myk1) + (k4.y < myk1) + (k4.z < myk1) + (k4.w < myk1);
                }
                if (r0 < K_NN) sSel[wave][r0] = myk0;
                if (r1 < K_NN) sSel[wave][r1] = myk1;
                __threadfence_block();

                const uint4 sA = *(const uint4*)&sSel[wave][0];
                const uint4 sB = *(const uint4*)&sSel[wave][4];
                const uint4 sC = *(const uint4*)&sSel[wave][8];
                const uint4 sD = *(const uint4*)&sSel[wave][12];
                sel[0]  = (uint32_t)__builtin_amdgcn_readfirstlane((int)sA.x);
                sel[1]  = (uint32_t)__builtin_amdgcn_readfirstlane((int)sA.y);
                sel[2]  = (uint32_t)__builtin_amdgcn_readfirstlane((int)sA.z);
                sel[3]  = (uint32_t)__builtin_amdgcn_readfirstlane((int)sA.w);
                sel[4]  = (uint32_t)__builtin_amdgcn_readfirstlane((int)sB.x);
                sel[5]  = (uint32_t)__builtin_amdgcn_readfirstlane((int)sB.y);
                sel[6]  = (uint32_t)__builtin_amdgcn_readfirstlane((int)sB.z);
                sel[7]  = (uint32_t)__builtin_amdgcn_readfirstlane((int)sB.w);
                sel[8]  = (uint32_t)__builtin_amdgcn_readfirstlane((int)sC.x);
                sel[9]  = (uint32_t)__builtin_amdgcn_readfirstlane((int)sC.y);
                sel[10] = (uint32_t)__builtin_amdgcn_readfirstlane((int)sC.z);
                sel[11] = (uint32_t)__builtin_amdgcn_readfirstlane((int)sC.w);
                sel[12] = (uint32_t)__builtin_amdgcn_readfirstlane((int)sD.x);
                sel[13] = (uint32_t)__builtin_amdgcn_readfirstlane((int)sD.y);
                sel[14] = (uint32_t)__builtin_amdgcn_readfirstlane((int)sD.z);
                sel[15] = (uint32_t)__builtin_amdgcn_readfirstlane((int)sD.w);
                done = true;
            }
        }
    }

    if (!done) {
        // ---------- exact ring loop with insert path ----------
        for (int r = 1;; ++r) {
            uint32_t kl[K_NN];
#pragma unroll
            for (int j = 0; j < K_NN; ++j) kl[j] = PADKEY + 16 + j;
            if (r > 1) {
                uint32_t seed = 0xFFFFFFFFu;
#pragma unroll
                for (int j = 0; j < K_NN; ++j) if (lane == j) seed = sel[j];
                kl[0] = seed;
            }
            uint32_t curmax = kl[0];
#pragma unroll
            for (int j = 1; j < K_NN; ++j) curmax = max(curmax, kl[j]);

            for (int dz = -r; dz <= r; ++dz) {
                const int cz = scz + dz; if ((unsigned)cz >= CZ) continue;
                for (int dy = -r; dy <= r; ++dy) {
                    const int cy = scy + dy; if ((unsigned)cy >= CY) continue;
                    const int rowb = (cz * CY + cy) * CX;
                    const bool fullrow = (r == 1) || (max(abs(dz), abs(dy)) == r);
                    int xl[2], xh[2];
                    if (fullrow) {
                        xl[0] = max(scx - r, 0); xh[0] = min(scx + r, CX - 1);
                        xl[1] = 1; xh[1] = 0;
                    } else {
                        xl[0] = scx - r; xh[0] = scx - r;
                        xl[1] = scx + r; xh[1] = scx + r;
                        if (xl[0] < 0)      { xl[0] = 1; xh[0] = 0; }
                        if (xh[1] > CX - 1) { xl[1] = 1; xh[1] = 0; }
                    }
#pragma unroll
                    for (int q = 0; q < 2; ++q) {
                        if (xl[q] > xh[q]) continue;
                        const int2 mlo = mb[rowb + xl[q]];
                        const int2 mhi = mb[rowb + xh[q]];
                        const int st = mlo.x, ln = mhi.x + mhi.y - st;
                        for (int o = 0; o < ln; o += 64) {
                            const int j2 = o + lane;
                            const bool act = j2 < ln;
                            const int a = st + (act ? j2 : 0);
                            const float4 p = sb[a];
                            const float d0 = s0 - p.x, d1 = s1 - p.y, d2c = s2 - p.z;
                            const float d2 = d0 * d0 + d1 * d1 + d2c * d2c;
                            uint32_t kv = ((uint32_t)d2 << 14) | (uint32_t)__float_as_int(p.w);
                            kv = act ? kv : 0xFFFFFFFFu;
                            if (kv < curmax) {
#pragma unroll
                                for (int j = 0; j < K_NN; ++j)
                                    kl[j] = (kl[j] == curmax) ? kv : kl[j];
                                curmax = kl[0];
#pragma unroll
                                for (int j = 1; j < K_NN; ++j) curmax = max(curmax, kl[j]);
                            }
                        }
                    }
                }
            }
            merge_extract<K_NN>(kl, sel);
            const uint32_t d16 = sel[K_NN - 1] >> 14;
            if (d16 <= (uint32_t)(256 * r * r) || r >= rcov) break;
        }
    }

    // ---- weights + normalized feature aggregation (float2 per lane) ----
    float w[K_NN];
    float wsum = 0.f;
#pragma unroll
    for (int j = 0; j < K_NN; ++j) {
        w[j] = __expf(-0.5f * (float)(sel[j] >> 14));
        wsum += w[j];
    }
    const float inv = 1.0f / wsum;

    const float* fb = tfeat + (size_t)b * NA_ * CH;
    float2 acc = make_float2(0.f, 0.f);
#pragma unroll
    for (int j = 0; j < K_NN; ++j) {
        const int idx = (int)(sel[j] & 16383u);
        const float ww = w[j] * inv;
        const float2 v = ((const float2*)(fb + (size_t)idx * CH))[lane];
        acc.x += ww * v.x; acc.y += ww * v.y;
    }

    float2* o = (float2*)(out + ((size_t)b * NB_ + n) * CH);
    o[lane] = acc;
}

// ---------------- launch ----------------

extern "C" void kernel_launch(void* const* d_in, const int* in_sizes, int n_in,
                              void* d_out, int out_size, void* d_ws, size_t ws_size,
                              hipStream_t stream) {
    const float* tfeat = (const float*)d_in[0];   // [B,NA,C]
    const float* tpos  = (const float*)d_in[1];   // [B,NA,3]
    const float* spos  = (const float*)d_in[2];   // [B,NB,3]
    float* out = (float*)d_out;                   // [B,NB,C]

    char* ws = (char*)d_ws;
    int*    partial = (int*)(ws);
    int2*   meta    = (int2*)(ws + OFF_META);
    int*    cursor  = (int*)(ws + OFF_CURSOR);
    float4* sorted  = (float4*)(ws + OFF_SORTED);

    count_hist<<<16, 256, 0, stream>>>(tpos, partial);
    scan_kernel<<<BATCH, 1024, 0, stream>>>(partial, meta, cursor);
    scatter_kernel<<<(BATCH * NA_) / 256, 256, 0, stream>>>(tpos, cursor, sorted);
    knn_cells_kernel<<<BATCH * (NB_ / 4), 256, 0, stream>>>(tfeat, spos, meta, sorted, out);
}